// Round 14
// baseline (7048.135 us; speedup 1.0000x reference)
//
#include <hip/hip_runtime.h>
#include <hip/hip_bf16.h>

typedef __attribute__((ext_vector_type(8))) short bf16x8;
typedef __attribute__((ext_vector_type(4))) float f32x4;
typedef unsigned short u16;
typedef unsigned int u32;

static constexpr int B_ = 64, S_ = 1024, I_ = 1024, H_ = 1024;

__device__ __forceinline__ u16 f2b(float f) {
  union { float f; unsigned u; } v; v.f = f;
  unsigned r = v.u + 0x7FFF + ((v.u >> 16) & 1);
  return (u16)(r >> 16);
}
__device__ __forceinline__ float b2f(u16 u) {
  union { unsigned u; float f; } v; v.u = ((unsigned)u) << 16;
  return v.f;
}

// ---- device-coherent (LLC) accesses: bypass L1+L2 via sc0 sc1 ----
__device__ __forceinline__ void st_coh_u16(void* p, unsigned v) {
  asm volatile("global_store_short %0, %1, off sc0 sc1" :: "v"(p), "v"(v) : "memory");
}
__device__ __forceinline__ void st_coh_u32(void* p, unsigned v) {
  asm volatile("global_store_dword %0, %1, off sc0 sc1" :: "v"(p), "v"(v) : "memory");
}
__device__ __forceinline__ uint4 ld_coh_b128_wait(const void* p) {
  uint4 r;
  asm volatile("global_load_dwordx4 %0, %1, off sc0 sc1\n\ts_waitcnt vmcnt(0)"
               : "=v"(r) : "v"(p) : "memory");
  return r;
}
__device__ __forceinline__ uint4 ld_coh_b128(const void* p) {
  uint4 r;
  asm volatile("global_load_dwordx4 %0, %1, off sc0 sc1" : "=v"(r) : "v"(p) : "memory");
  return r;
}

// ---------------- fp32 -> bf16 cast (grid-stride, float4) ----------------
__global__ void cvt_f32_bf16(const float* __restrict__ src, u16* __restrict__ dst, int n4) {
  int i = blockIdx.x * blockDim.x + threadIdx.x;
  int stride = gridDim.x * blockDim.x;
  for (; i < n4; i += stride) {
    float4 f = ((const float4*)src)[i];
    ushort4 o;
    o.x = f2b(f.x); o.y = f2b(f.y); o.z = f2b(f.z); o.w = f2b(f.w);
    ((ushort4*)dst)[i] = o;
  }
}

// ---------------- input projection GEMM: x_g = inputs @ w_ig^T + b_ig ----------------
__global__ __launch_bounds__(256) void xproj_gemm(
    const u16* __restrict__ A, const u16* __restrict__ W,
    const float* __restrict__ b_ir, const float* __restrict__ b_iz, const float* __restrict__ b_in,
    u16* __restrict__ X) {
  __shared__ u16 smem[16384];                 // As[8192] + Bs[8192]; reused for out tile
  u16* As = smem;
  u16* Bs = smem + 8192;
  int bid = blockIdx.x;
  int mt = bid / 24; int rr = bid % 24; int g = rr >> 3; int nt = rr & 7;
  int tid = threadIdx.x, lane = tid & 63, wid = tid >> 6;
  int wr = wid >> 1, wc = wid & 1;
  const u16* A0 = A + (size_t)mt * 128 * 1024;
  const u16* W0 = W + (size_t)g * 1024 * 1024 + (size_t)nt * 128 * 1024;
  f32x4 acc[4][4] = {};
  for (int k0 = 0; k0 < 1024; k0 += 64) {
    __syncthreads();
#pragma unroll
    for (int j = 0; j < 4; ++j) {
      int c = wid * 4 + j;
      int row = c * 8 + (lane >> 3);
      int ke = (lane & 7) * 8;
      __builtin_amdgcn_global_load_lds(
          (const __attribute__((address_space(1))) void*)(A0 + row * 1024 + k0 + ke),
          (__attribute__((address_space(3))) void*)(As + c * 512), 16, 0, 0);
      __builtin_amdgcn_global_load_lds(
          (const __attribute__((address_space(1))) void*)(W0 + row * 1024 + k0 + ke),
          (__attribute__((address_space(3))) void*)(Bs + c * 512), 16, 0, 0);
    }
    asm volatile("s_waitcnt vmcnt(0)" ::: "memory");
    __syncthreads();
#pragma unroll
    for (int kk = 0; kk < 64; kk += 32) {
      bf16x8 a[4], b[4];
      int rbase = lane & 15;
      int koff = kk + ((lane >> 4) << 3);
#pragma unroll
      for (int mi = 0; mi < 4; ++mi)
        a[mi] = *(const bf16x8*)(As + (wr * 64 + mi * 16 + rbase) * 64 + koff);
#pragma unroll
      for (int ni = 0; ni < 4; ++ni)
        b[ni] = *(const bf16x8*)(Bs + (wc * 64 + ni * 16 + rbase) * 64 + koff);
#pragma unroll
      for (int mi = 0; mi < 4; ++mi)
#pragma unroll
        for (int ni = 0; ni < 4; ++ni)
          acc[mi][ni] = __builtin_amdgcn_mfma_f32_16x16x32_bf16(a[mi], b[ni], acc[mi][ni], 0, 0, 0);
    }
  }
  __syncthreads();
  const float* bp = (g == 0) ? b_ir : (g == 1) ? b_iz : b_in;
  float bias[4];
#pragma unroll
  for (int ni = 0; ni < 4; ++ni)
    bias[ni] = bp[nt * 128 + wc * 64 + ni * 16 + (lane & 15)];
#pragma unroll
  for (int mi = 0; mi < 4; ++mi)
#pragma unroll
    for (int ni = 0; ni < 4; ++ni) {
      int ml = wr * 64 + mi * 16 + ((lane >> 4) << 2);
      int nl = wc * 64 + ni * 16 + (lane & 15);
#pragma unroll
      for (int i = 0; i < 4; ++i)
        smem[(ml + i) * 128 + nl] = f2b(acc[mi][ni][i] + bias[ni]);
    }
  __syncthreads();
#pragma unroll
  for (int j = 0; j < 8; ++j) {
    int c = tid + j * 256;           // 2048 chunks of 16B
    int rowl = c >> 4;
    int n0 = (c & 15) * 8;
    int m = mt * 128 + rowl;
    int b = m >> 10, s = m & 1023;
    bf16x8 v = *(const bf16x8*)(smem + rowl * 128 + n0);
    *(bf16x8*)(X + ((size_t)((s * 64 + b) * 3 + g)) * 1024 + nt * 128 + n0) = v;
  }
}

// ---------------- persistent GRU scan, WAVE-granular flag sync (R14) ----------------
// 256 WGs x 256 thr; WG (mq=wg&3, cb=wg>>2) owns batch rows [mq*16,+16), cols [cb*16,+16)
// flag[mq][cb][w] = # of h buffers written by wave w of WG (mq,cb). Wave w's h-stores cover
// rows [mq*16+4w,+4) (its 64 lanes). Producer wave: h-store -> own vmcnt(0) -> lane0 flag.
// NO end-of-step __syncthreads (2 barriers/step). Consumer: each lane reads its WG's 4 flags
// as one uint4 (16B contiguous) and requires all >= tgt — covers producers of all 16 rows.
// Overwrite guard unchanged at wave granularity: per-wave program order stage(t) < flag(t+2).
// hbf double-buffered bf16 [2][64][1024]; all cross-WG data via sc0 sc1 (LLC, fence-free).
// Plain launch (131KB LDS -> 1 WG/CU, grid == 256 == #CUs). wfrag: weights in registers.
__global__ __launch_bounds__(256) void gru_scan(
    const u16* __restrict__ xbuf, const float* __restrict__ h0p,
    const float* __restrict__ w_hr, const float* __restrict__ w_hz, const float* __restrict__ w_hn,
    const float* __restrict__ b_hr, const float* __restrict__ b_hz, const float* __restrict__ b_hn,
    u16* __restrict__ hbf, float* __restrict__ out, u32* __restrict__ flags) {
  extern __shared__ u16 smem[];
  u16* Wl = smem;                       // 3*16*1024 u16 = 96KB (persistent, swizzled)
  u16* Hl = smem + 49152;               // 16*1024 u16 = 32KB (per-step h slice)
  float* ex = (float*)(smem + 65536);   // 3KB (separate: MFMA+ex-write one phase)
  int tid = threadIdx.x, lane = tid & 63, wid = tid >> 6;
  int wg = blockIdx.x, mq = wg & 3, cb = wg >> 2;
  u32* gflags = flags + mq * 256;       // [64 cb][4 w] u32

  // load recurrent weights for our 16 columns x 3 gates into LDS (once)
  for (int idx = tid; idx < 3 * 2048; idx += 256) {
    int g = idx >> 11; int rem = idx & 2047; int row = rem >> 7; int ch = rem & 127;
    const float* wsrc = (g == 0) ? w_hr : (g == 1) ? w_hz : w_hn;
    const float* src = wsrc + (size_t)(cb * 16 + row) * 1024 + ch * 8;
    float4 f0 = *(const float4*)src;
    float4 f1 = *(const float4*)(src + 4);
    bf16x8 v;
    v[0] = (short)f2b(f0.x); v[1] = (short)f2b(f0.y); v[2] = (short)f2b(f0.z); v[3] = (short)f2b(f0.w);
    v[4] = (short)f2b(f1.x); v[5] = (short)f2b(f1.y); v[6] = (short)f2b(f1.z); v[7] = (short)f2b(f1.w);
    int kbyte = (ch * 16) ^ ((row & 7) << 4);
    *(bf16x8*)((char*)(Wl + g * 16384) + row * 2048 + kbyte) = v;
  }

  int b_l = tid >> 4, c_l = tid & 15;
  int bg = mq * 16 + b_l, cg = cb * 16 + c_l;
  float h = h0p[bg * 1024 + cg];
  float bhr = b_hr[cg], bhz = b_hz[cg], bhn = b_hn[cg];
  st_coh_u16(hbf + bg * 1024 + cg, f2b(h));       // buffer 0
  asm volatile("s_waitcnt vmcnt(0)" ::: "memory"); // own wave's h0 acked at LLC
  __syncthreads();                                 // Wl writes complete (wfrag below)
  if (lane == 0) st_coh_u32(gflags + cb * 4 + wid, 1u);

  // preload this wave's B-fragments (gate weights) into registers (rule #20: static idx)
  bf16x8 wfrag[32];
  {
    const char* wbase = (const char*)(Wl + (wid < 3 ? wid : 0) * 16384);
    int row = lane & 15;
    int klane = (lane >> 4) << 4;
    int sw = (row & 7) << 4;
#pragma unroll
    for (int ks = 0; ks < 32; ++ks)
      wfrag[ks] = *(const bf16x8*)(wbase + row * 2048 + (((ks << 6) + klane) ^ sw));
  }

  const size_t outb = (size_t)bg * S_ * H_;
  for (int t = 0; t < S_; ++t) {
    const u16* rdbuf = hbf + (size_t)(t & 1) * 65536;
    u16* wrbuf = hbf + (size_t)((t + 1) & 1) * 65536;

    // x prefetch BEFORE the poll: HBM latency hides under the flag wait (R7-proven)
    const u16* xp = xbuf + (size_t)(t * 64 + bg) * 3072 + cg;
    u16 xr_u = xp[0], xz_u = xp[1024], xn_u = xp[2048];

    // poll: lane reads WG 'lane's 4 wave-flags as uint4; all 256 flags must reach tgt
    {
      unsigned tgt = (unsigned)(t + 1);
      const u32* fp = gflags + lane * 4;
      for (;;) {
        uint4 v = ld_coh_b128_wait(fp);
        __builtin_amdgcn_sched_barrier(0);
        bool ok = (v.x >= tgt) & (v.y >= tgt) & (v.z >= tgt) & (v.w >= tgt);
        if (__all((int)ok)) break;
        __builtin_amdgcn_s_sleep(1);
      }
    }

    // stage our 16-row h slice (all 1024 cols) into LDS, swizzled (coh loads)
    uint4 tmp[8];
#pragma unroll
    for (int j = 0; j < 8; ++j) {
      int ch2 = tid + j * 256;          // 2048 chunks of 16B
      int row = ch2 >> 7, kc = ch2 & 127;
      tmp[j] = ld_coh_b128(rdbuf + (mq * 16 + row) * 1024 + kc * 8);
    }
    asm volatile("s_waitcnt vmcnt(0)" ::: "memory");
    __builtin_amdgcn_sched_barrier(0);
#pragma unroll
    for (int j = 0; j < 8; ++j) {
      int ch2 = tid + j * 256;
      int row = ch2 >> 7, kc = ch2 & 127;
      int kbyte = (kc * 16) ^ ((row & 7) << 4);
      *(uint4*)((char*)Hl + row * 2048 + kbyte) = tmp[j];
    }
    __syncthreads();                     // (A): Hl fully staged

    f32x4 acc0 = {}, acc1 = {}, acc2 = {}, acc3 = {};
    if (wid < 3) {                       // wave g computes gate g: [16x1024]x[1024x16]
      const char* hbase = (const char*)Hl;
      int row = lane & 15;
      int klane = (lane >> 4) << 4;      // 16B sub-chunk within 64B k-step
      int sw = (row & 7) << 4;
#pragma unroll
      for (int ks = 0; ks < 32; ks += 4) {
#pragma unroll
        for (int q = 0; q < 4; ++q) {
          int off = row * 2048 + ((((ks + q) << 6) + klane) ^ sw);
          bf16x8 av = *(const bf16x8*)(hbase + off);
          if (q == 0) acc0 = __builtin_amdgcn_mfma_f32_16x16x32_bf16(av, wfrag[ks + q], acc0, 0, 0, 0);
          else if (q == 1) acc1 = __builtin_amdgcn_mfma_f32_16x16x32_bf16(av, wfrag[ks + q], acc1, 0, 0, 0);
          else if (q == 2) acc2 = __builtin_amdgcn_mfma_f32_16x16x32_bf16(av, wfrag[ks + q], acc2, 0, 0, 0);
          else acc3 = __builtin_amdgcn_mfma_f32_16x16x32_bf16(av, wfrag[ks + q], acc3, 0, 0, 0);
        }
      }
      f32x4 acc = (acc0 + acc1) + (acc2 + acc3);
      int col = lane & 15, r0 = (lane >> 4) << 2;
#pragma unroll
      for (int i = 0; i < 4; ++i)
        ex[wid * 256 + (r0 + i) * 16 + col] = acc[i];
    }
    __syncthreads();                     // (B): ex ready

    float hr = ex[b_l * 16 + c_l] + bhr;
    float hz = ex[256 + b_l * 16 + c_l] + bhz;
    float hn = ex[512 + b_l * 16 + c_l] + bhn;
    float xr = b2f(xr_u), xz = b2f(xz_u), xn = b2f(xn_u);
    float r = 1.f / (1.f + __expf(-(xr + hr)));
    float z = 1.f / (1.f + __expf(-(xz + hz)));
    float nn = 1.f - 2.f / (__expf(2.f * (xn + r * hn)) + 1.f);
    h = (1.f - z) * nn + z * h;
    // producer: h(t+1) -> LLC; own-wave drain; per-wave flag. No WG barrier.
    st_coh_u16(wrbuf + bg * 1024 + cg, f2b(h));
    asm volatile("s_waitcnt vmcnt(0)" ::: "memory");   // this wave's h stores acked
    if (lane == 0) st_coh_u32(gflags + cb * 4 + wid, (unsigned)(t + 2));
    out[outb + (size_t)t * H_ + cg] = h;  // plain store, overlaps next poll
  }
  out[(size_t)B_ * S_ * H_ + bg * 1024 + cg] = h; // h_final
}

// ---------------- launcher ----------------
extern "C" void kernel_launch(void* const* d_in, const int* in_sizes, int n_in,
                              void* d_out, int out_size, void* d_ws, size_t ws_size,
                              hipStream_t stream) {
  const float* inputs = (const float*)d_in[0];
  const float* h0p    = (const float*)d_in[1];
  const float* w_ir   = (const float*)d_in[2];
  const float* w_iz   = (const float*)d_in[3];
  const float* w_in   = (const float*)d_in[4];
  const float* b_ir   = (const float*)d_in[5];
  const float* b_iz   = (const float*)d_in[6];
  const float* b_in   = (const float*)d_in[7];
  const float* w_hr   = (const float*)d_in[8];
  const float* w_hz   = (const float*)d_in[9];
  const float* w_hn   = (const float*)d_in[10];
  const float* b_hr   = (const float*)d_in[11];
  const float* b_hz   = (const float*)d_in[12];
  const float* b_hn   = (const float*)d_in[13];
  float* out = (float*)d_out;

  size_t xbytes  = (size_t)S_ * B_ * 3 * H_ * 2;   // 384 MB
  size_t wibytes = (size_t)3 * H_ * I_ * 2;        // 6 MB
  size_t hbytes  = (size_t)2 * B_ * H_ * 2;        // 256 KB (double-buffered)
  size_t flagbytes = 4096;                         // [4 mq][64 cb][4 w] u32
  if (ws_size < xbytes + wibytes + hbytes + flagbytes) return;

  u16* xbuf = (u16*)d_ws;
  u16* wibf = (u16*)((char*)d_ws + xbytes);
  u16* hbf  = (u16*)((char*)d_ws + xbytes + wibytes);
  u32* flags = (u32*)((char*)d_ws + xbytes + wibytes + hbytes);
  u16* Abf  = (u16*)d_out;   // 128 MB scratch inside 256 MB output region (GEMM phase only)

  (void)hipMemsetAsync(flags, 0, flagbytes, stream);

  cvt_f32_bf16<<<2048, 256, 0, stream>>>(inputs, Abf, B_ * S_ * I_ / 4);
  cvt_f32_bf16<<<256, 256, 0, stream>>>(w_ir, wibf,               H_ * I_ / 4);
  cvt_f32_bf16<<<256, 256, 0, stream>>>(w_iz, wibf + H_ * I_,     H_ * I_ / 4);
  cvt_f32_bf16<<<256, 256, 0, stream>>>(w_in, wibf + 2 * H_ * I_, H_ * I_ / 4);

  xproj_gemm<<<12288, 256, 0, stream>>>(Abf, wibf, b_ir, b_iz, b_in, xbuf);

  // Plain launch (R11-proven): no grid.sync; co-residency resource-guaranteed
  // (131KB dynamic LDS -> 1 WG/CU; grid 256 == CU count).
  (void)hipFuncSetAttribute((const void*)gru_scan, hipFuncAttributeMaxDynamicSharedMemorySize, 135168);
  gru_scan<<<dim3(256), dim3(256), 134144, stream>>>(
      xbuf, h0p, w_hr, w_hz, w_hn, b_hr, b_hz, b_hn, hbf, out, flags);
}

// Round 15
// 4589.040 us; speedup vs baseline: 1.5359x; 1.5359x over previous
//
#include <hip/hip_runtime.h>
#include <hip/hip_bf16.h>

typedef __attribute__((ext_vector_type(8))) short bf16x8;
typedef __attribute__((ext_vector_type(4))) float f32x4;
typedef unsigned short u16;
typedef unsigned int u32;

static constexpr int B_ = 64, S_ = 1024, I_ = 1024, H_ = 1024;

__device__ __forceinline__ u16 f2b(float f) {
  union { float f; unsigned u; } v; v.f = f;
  unsigned r = v.u + 0x7FFF + ((v.u >> 16) & 1);
  return (u16)(r >> 16);
}
__device__ __forceinline__ float b2f(u16 u) {
  union { unsigned u; float f; } v; v.u = ((unsigned)u) << 16;
  return v.f;
}

// ---- device-coherent (LLC) accesses: bypass L1+L2 via sc0 sc1 ----
__device__ __forceinline__ void st_coh_u16(void* p, unsigned v) {
  asm volatile("global_store_short %0, %1, off sc0 sc1" :: "v"(p), "v"(v) : "memory");
}
__device__ __forceinline__ void st_coh_u32(void* p, unsigned v) {
  asm volatile("global_store_dword %0, %1, off sc0 sc1" :: "v"(p), "v"(v) : "memory");
}
__device__ __forceinline__ unsigned ld_coh_u32_wait(const void* p) {
  unsigned r;
  asm volatile("global_load_dword %0, %1, off sc0 sc1\n\ts_waitcnt vmcnt(0)"
               : "=v"(r) : "v"(p) : "memory");
  return r;
}
__device__ __forceinline__ uint4 ld_coh_b128(const void* p) {
  uint4 r;
  asm volatile("global_load_dwordx4 %0, %1, off sc0 sc1" : "=v"(r) : "v"(p) : "memory");
  return r;
}

// ---------------- fp32 -> bf16 cast (grid-stride, float4) ----------------
__global__ void cvt_f32_bf16(const float* __restrict__ src, u16* __restrict__ dst, int n4) {
  int i = blockIdx.x * blockDim.x + threadIdx.x;
  int stride = gridDim.x * blockDim.x;
  for (; i < n4; i += stride) {
    float4 f = ((const float4*)src)[i];
    ushort4 o;
    o.x = f2b(f.x); o.y = f2b(f.y); o.z = f2b(f.z); o.w = f2b(f.w);
    ((ushort4*)dst)[i] = o;
  }
}

// ---------------- input projection GEMM: x_g = inputs @ w_ig^T + b_ig ----------------
__global__ __launch_bounds__(256) void xproj_gemm(
    const u16* __restrict__ A, const u16* __restrict__ W,
    const float* __restrict__ b_ir, const float* __restrict__ b_iz, const float* __restrict__ b_in,
    u16* __restrict__ X) {
  __shared__ u16 smem[16384];                 // As[8192] + Bs[8192]; reused for out tile
  u16* As = smem;
  u16* Bs = smem + 8192;
  int bid = blockIdx.x;
  int mt = bid / 24; int rr = bid % 24; int g = rr >> 3; int nt = rr & 7;
  int tid = threadIdx.x, lane = tid & 63, wid = tid >> 6;
  int wr = wid >> 1, wc = wid & 1;
  const u16* A0 = A + (size_t)mt * 128 * 1024;
  const u16* W0 = W + (size_t)g * 1024 * 1024 + (size_t)nt * 128 * 1024;
  f32x4 acc[4][4] = {};
  for (int k0 = 0; k0 < 1024; k0 += 64) {
    __syncthreads();
#pragma unroll
    for (int j = 0; j < 4; ++j) {
      int c = wid * 4 + j;
      int row = c * 8 + (lane >> 3);
      int ke = (lane & 7) * 8;
      __builtin_amdgcn_global_load_lds(
          (const __attribute__((address_space(1))) void*)(A0 + row * 1024 + k0 + ke),
          (__attribute__((address_space(3))) void*)(As + c * 512), 16, 0, 0);
      __builtin_amdgcn_global_load_lds(
          (const __attribute__((address_space(1))) void*)(W0 + row * 1024 + k0 + ke),
          (__attribute__((address_space(3))) void*)(Bs + c * 512), 16, 0, 0);
    }
    asm volatile("s_waitcnt vmcnt(0)" ::: "memory");
    __syncthreads();
#pragma unroll
    for (int kk = 0; kk < 64; kk += 32) {
      bf16x8 a[4], b[4];
      int rbase = lane & 15;
      int koff = kk + ((lane >> 4) << 3);
#pragma unroll
      for (int mi = 0; mi < 4; ++mi)
        a[mi] = *(const bf16x8*)(As + (wr * 64 + mi * 16 + rbase) * 64 + koff);
#pragma unroll
      for (int ni = 0; ni < 4; ++ni)
        b[ni] = *(const bf16x8*)(Bs + (wc * 64 + ni * 16 + rbase) * 64 + koff);
#pragma unroll
      for (int mi = 0; mi < 4; ++mi)
#pragma unroll
        for (int ni = 0; ni < 4; ++ni)
          acc[mi][ni] = __builtin_amdgcn_mfma_f32_16x16x32_bf16(a[mi], b[ni], acc[mi][ni], 0, 0, 0);
    }
  }
  __syncthreads();
  const float* bp = (g == 0) ? b_ir : (g == 1) ? b_iz : b_in;
  float bias[4];
#pragma unroll
  for (int ni = 0; ni < 4; ++ni)
    bias[ni] = bp[nt * 128 + wc * 64 + ni * 16 + (lane & 15)];
#pragma unroll
  for (int mi = 0; mi < 4; ++mi)
#pragma unroll
    for (int ni = 0; ni < 4; ++ni) {
      int ml = wr * 64 + mi * 16 + ((lane >> 4) << 2);
      int nl = wc * 64 + ni * 16 + (lane & 15);
#pragma unroll
      for (int i = 0; i < 4; ++i)
        smem[(ml + i) * 128 + nl] = f2b(acc[mi][ni][i] + bias[ni]);
    }
  __syncthreads();
#pragma unroll
  for (int j = 0; j < 8; ++j) {
    int c = tid + j * 256;           // 2048 chunks of 16B
    int rowl = c >> 4;
    int n0 = (c & 15) * 8;
    int m = mt * 128 + rowl;
    int b = m >> 10, s = m & 1023;
    bf16x8 v = *(const bf16x8*)(smem + rowl * 128 + n0);
    *(bf16x8*)(X + ((size_t)((s * 64 + b) * 3 + g)) * 1024 + nt * 128 + n0) = v;
  }
}

// ---------------- persistent GRU scan, per-mq-group flag sync (R11, final) ----------------
// 256 WGs x 256 thr; WG (mq=wg&3, cb=wg>>2) owns batch rows [mq*16,+16), cols [cb*16,+16)
// Sync: only among the 64 WGs sharing mq. flag[mq*64+cb] = # of h buffers written.
// All cross-WG data (hbf, flags) moves via sc0 sc1 (LLC-coherent, fence-free).
// hbf double-buffered bf16 [2][64][1024]: step t reads buf[t&1], writes buf[(t+1)&1].
// Plain launch: no grid.sync; co-residency resource-guaranteed (131KB LDS -> 1 WG/CU,
// grid == 256 == #CUs). wfrag: recurrent weights in registers (halves MFMA-phase LDS reads).
// Protocol perturbations measured and rejected: R8 (x-prefetch after poll, +9%),
// R12 (tag-in-data, +55% from retry re-reads), R13 (pipelined poll, unsound),
// R14 (wave-granular flags, +71% from flag contention). This is the floor of this
// decomposition: ~3 serial LLC RTs + ~1.3us local work per step.
__global__ __launch_bounds__(256) void gru_scan(
    const u16* __restrict__ xbuf, const float* __restrict__ h0p,
    const float* __restrict__ w_hr, const float* __restrict__ w_hz, const float* __restrict__ w_hn,
    const float* __restrict__ b_hr, const float* __restrict__ b_hz, const float* __restrict__ b_hn,
    u16* __restrict__ hbf, float* __restrict__ out, u32* __restrict__ flags) {
  extern __shared__ u16 smem[];
  u16* Wl = smem;                       // 3*16*1024 u16 = 96KB (persistent, swizzled)
  u16* Hl = smem + 49152;               // 16*1024 u16 = 32KB (per-step h slice)
  float* ex = (float*)(smem + 65536);   // 3KB (separate: MFMA+ex-write one phase)
  int tid = threadIdx.x, lane = tid & 63, wid = tid >> 6;
  int wg = blockIdx.x, mq = wg & 3, cb = wg >> 2;
  u32* gflags = flags + mq * 64;

  // load recurrent weights for our 16 columns x 3 gates into LDS (once)
  for (int idx = tid; idx < 3 * 2048; idx += 256) {
    int g = idx >> 11; int rem = idx & 2047; int row = rem >> 7; int ch = rem & 127;
    const float* wsrc = (g == 0) ? w_hr : (g == 1) ? w_hz : w_hn;
    const float* src = wsrc + (size_t)(cb * 16 + row) * 1024 + ch * 8;
    float4 f0 = *(const float4*)src;
    float4 f1 = *(const float4*)(src + 4);
    bf16x8 v;
    v[0] = (short)f2b(f0.x); v[1] = (short)f2b(f0.y); v[2] = (short)f2b(f0.z); v[3] = (short)f2b(f0.w);
    v[4] = (short)f2b(f1.x); v[5] = (short)f2b(f1.y); v[6] = (short)f2b(f1.z); v[7] = (short)f2b(f1.w);
    int kbyte = (ch * 16) ^ ((row & 7) << 4);
    *(bf16x8*)((char*)(Wl + g * 16384) + row * 2048 + kbyte) = v;
  }

  int b_l = tid >> 4, c_l = tid & 15;
  int bg = mq * 16 + b_l, cg = cb * 16 + c_l;
  float h = h0p[bg * 1024 + cg];
  float bhr = b_hr[cg], bhz = b_hz[cg], bhn = b_hn[cg];
  st_coh_u16(hbf + bg * 1024 + cg, f2b(h));     // buffer 0
  __syncthreads();                              // drains all waves' vmcnt -> h0 at LLC
  if (tid == 0) st_coh_u32(gflags + cb, 1u);

  // preload this wave's B-fragments (gate weights) into registers (rule #20: static idx)
  bf16x8 wfrag[32];
  {
    const char* wbase = (const char*)(Wl + (wid < 3 ? wid : 0) * 16384);
    int row = lane & 15;
    int klane = (lane >> 4) << 4;
    int sw = (row & 7) << 4;
#pragma unroll
    for (int ks = 0; ks < 32; ++ks)
      wfrag[ks] = *(const bf16x8*)(wbase + row * 2048 + (((ks << 6) + klane) ^ sw));
  }

  const size_t outb = (size_t)bg * S_ * H_;
  for (int t = 0; t < S_; ++t) {
    const u16* rdbuf = hbf + (size_t)(t & 1) * 65536;
    u16* wrbuf = hbf + (size_t)((t + 1) & 1) * 65536;

    // x prefetch BEFORE the poll: HBM latency hides under the flag wait (R7-proven)
    const u16* xp = xbuf + (size_t)(t * 64 + bg) * 3072 + cg;
    u16 xr_u = xp[0], xz_u = xp[1024], xn_u = xp[2048];

    // poll: all 4 waves spin until every WG in our mq-group has written h(t)
    {
      unsigned tgt = (unsigned)(t + 1);
      const u32* fp = gflags + lane;
      unsigned v = ld_coh_u32_wait(fp);
      while (!__all((int)(v >= tgt))) {
        __builtin_amdgcn_s_sleep(1);
        v = ld_coh_u32_wait(fp);
      }
    }

    // stage our 16-row h slice (all 1024 cols) into LDS, swizzled (coh loads)
    uint4 tmp[8];
#pragma unroll
    for (int j = 0; j < 8; ++j) {
      int ch2 = tid + j * 256;          // 2048 chunks of 16B
      int row = ch2 >> 7, kc = ch2 & 127;
      tmp[j] = ld_coh_b128(rdbuf + (mq * 16 + row) * 1024 + kc * 8);
    }
    asm volatile("s_waitcnt vmcnt(0)" ::: "memory");
    __builtin_amdgcn_sched_barrier(0);
#pragma unroll
    for (int j = 0; j < 8; ++j) {
      int ch2 = tid + j * 256;
      int row = ch2 >> 7, kc = ch2 & 127;
      int kbyte = (kc * 16) ^ ((row & 7) << 4);
      *(uint4*)((char*)Hl + row * 2048 + kbyte) = tmp[j];
    }
    __syncthreads();                     // (A): Hl fully staged

    f32x4 acc0 = {}, acc1 = {}, acc2 = {}, acc3 = {};
    if (wid < 3) {                       // wave g computes gate g: [16x1024]x[1024x16]
      const char* hbase = (const char*)Hl;
      int row = lane & 15;
      int klane = (lane >> 4) << 4;      // 16B sub-chunk within 64B k-step
      int sw = (row & 7) << 4;
#pragma unroll
      for (int ks = 0; ks < 32; ks += 4) {
#pragma unroll
        for (int q = 0; q < 4; ++q) {
          int off = row * 2048 + ((((ks + q) << 6) + klane) ^ sw);
          bf16x8 av = *(const bf16x8*)(hbase + off);
          if (q == 0) acc0 = __builtin_amdgcn_mfma_f32_16x16x32_bf16(av, wfrag[ks + q], acc0, 0, 0, 0);
          else if (q == 1) acc1 = __builtin_amdgcn_mfma_f32_16x16x32_bf16(av, wfrag[ks + q], acc1, 0, 0, 0);
          else if (q == 2) acc2 = __builtin_amdgcn_mfma_f32_16x16x32_bf16(av, wfrag[ks + q], acc2, 0, 0, 0);
          else acc3 = __builtin_amdgcn_mfma_f32_16x16x32_bf16(av, wfrag[ks + q], acc3, 0, 0, 0);
        }
      }
      f32x4 acc = (acc0 + acc1) + (acc2 + acc3);
      int col = lane & 15, r0 = (lane >> 4) << 2;
#pragma unroll
      for (int i = 0; i < 4; ++i)
        ex[wid * 256 + (r0 + i) * 16 + col] = acc[i];
    }
    __syncthreads();                     // (B): ex ready

    float hr = ex[b_l * 16 + c_l] + bhr;
    float hz = ex[256 + b_l * 16 + c_l] + bhz;
    float hn = ex[512 + b_l * 16 + c_l] + bhn;
    float xr = b2f(xr_u), xz = b2f(xz_u), xn = b2f(xn_u);
    float r = 1.f / (1.f + __expf(-(xr + hr)));
    float z = 1.f / (1.f + __expf(-(xz + hz)));
    float nn = 1.f - 2.f / (__expf(2.f * (xn + r * hn)) + 1.f);
    h = (1.f - z) * nn + z * h;
    st_coh_u16(wrbuf + bg * 1024 + cg, f2b(h));   // h(t+1) -> LLC
    __syncthreads();                              // drain: all waves' h stores acked
    if (tid == 0) st_coh_u32(gflags + cb, (unsigned)(t + 2));
    out[outb + (size_t)t * H_ + cg] = h;          // plain store, overlaps next poll
  }
  out[(size_t)B_ * S_ * H_ + bg * 1024 + cg] = h; // h_final
}

// ---------------- launcher ----------------
extern "C" void kernel_launch(void* const* d_in, const int* in_sizes, int n_in,
                              void* d_out, int out_size, void* d_ws, size_t ws_size,
                              hipStream_t stream) {
  const float* inputs = (const float*)d_in[0];
  const float* h0p    = (const float*)d_in[1];
  const float* w_ir   = (const float*)d_in[2];
  const float* w_iz   = (const float*)d_in[3];
  const float* w_in   = (const float*)d_in[4];
  const float* b_ir   = (const float*)d_in[5];
  const float* b_iz   = (const float*)d_in[6];
  const float* b_in   = (const float*)d_in[7];
  const float* w_hr   = (const float*)d_in[8];
  const float* w_hz   = (const float*)d_in[9];
  const float* w_hn   = (const float*)d_in[10];
  const float* b_hr   = (const float*)d_in[11];
  const float* b_hz   = (const float*)d_in[12];
  const float* b_hn   = (const float*)d_in[13];
  float* out = (float*)d_out;

  size_t xbytes  = (size_t)S_ * B_ * 3 * H_ * 2;   // 384 MB
  size_t wibytes = (size_t)3 * H_ * I_ * 2;        // 6 MB
  size_t hbytes  = (size_t)2 * B_ * H_ * 2;        // 256 KB (double-buffered)
  size_t flagbytes = 1024;
  if (ws_size < xbytes + wibytes + hbytes + flagbytes) return;

  u16* xbuf = (u16*)d_ws;
  u16* wibf = (u16*)((char*)d_ws + xbytes);
  u16* hbf  = (u16*)((char*)d_ws + xbytes + wibytes);
  u32* flags = (u32*)((char*)d_ws + xbytes + wibytes + hbytes);
  u16* Abf  = (u16*)d_out;   // 128 MB scratch inside 256 MB output region (GEMM phase only)

  (void)hipMemsetAsync(flags, 0, flagbytes, stream);

  cvt_f32_bf16<<<2048, 256, 0, stream>>>(inputs, Abf, B_ * S_ * I_ / 4);
  cvt_f32_bf16<<<256, 256, 0, stream>>>(w_ir, wibf,               H_ * I_ / 4);
  cvt_f32_bf16<<<256, 256, 0, stream>>>(w_iz, wibf + H_ * I_,     H_ * I_ / 4);
  cvt_f32_bf16<<<256, 256, 0, stream>>>(w_in, wibf + 2 * H_ * I_, H_ * I_ / 4);

  xproj_gemm<<<12288, 256, 0, stream>>>(Abf, wibf, b_ir, b_iz, b_in, xbuf);

  // Plain launch: no grid.sync; co-residency resource-guaranteed
  // (131KB dynamic LDS -> 1 WG/CU; grid 256 == CU count).
  (void)hipFuncSetAttribute((const void*)gru_scan, hipFuncAttributeMaxDynamicSharedMemorySize, 135168);
  gru_scan<<<dim3(256), dim3(256), 134144, stream>>>(
      xbuf, h0p, w_hr, w_hz, w_hn, b_hr, b_hz, b_hn, hbf, out, flags);
}